// Round 1
// baseline (2721.292 us; speedup 1.0000x reference)
//
#include <hip/hip_runtime.h>
#include <hip/hip_bf16.h>

#define IGNORE_INDEX (-100)

// Problem constants (fixed by the reference setup).
constexpr int Nrows = 8192;   // B*S
constexpr int Dk    = 2048;   // hidden
constexpr int Vv    = 32000;  // vocab

// GEMM tiling.
constexpr int BM = 128;
constexpr int BN = 128;
constexpr int BK = 64;
constexpr int NT  = Vv / BN;  // 250 vocab tiles
constexpr int NTP = 256;      // padded stride for partials

typedef __attribute__((ext_vector_type(8))) short   short8;
typedef __attribute__((ext_vector_type(8))) __bf16  bf16x8;
typedef __attribute__((ext_vector_type(4))) float   f32x4;

static __device__ __forceinline__ unsigned pack_bf16x2(float x, float y) {
    __hip_bfloat162 h = __float22bfloat162_rn(make_float2(x, y));
    unsigned u;
    __builtin_memcpy(&u, &h, 4);
    return u;
}

// Kernel 1: tiled bf16-MFMA GEMM computing per-(row, vocab-tile) partial
// (max, sum_exp) of the logits. A = h [Nrows x Dk] f32 row-major,
// B = W [Vv x Dk] f32 row-major; logits = A * B^T.
__global__ __launch_bounds__(256, 2)
void lce_gemm_lse(const float* __restrict__ hx, const float* __restrict__ wx,
                  float* __restrict__ pmax, float* __restrict__ psum) {
    __shared__ unsigned short As[BM * BK];
    __shared__ unsigned short Bs[BN * BK];
    __shared__ float redmax[BM][2];
    __shared__ float redsum[BM][2];

    const int t    = threadIdx.x;
    const int lane = t & 63;
    const int wid  = t >> 6;
    const int wrow = wid >> 1;   // 0..1 (row half of the 128x128 tile)
    const int wcol = wid & 1;    // 0..1 (col half)
    const int l15  = lane & 15;
    const int l4   = lane >> 4;

    const int rowBase = blockIdx.x * BM;
    const int colBase = blockIdx.y * BN;

    f32x4 acc[4][4] = {};  // 4x4 fragments of 16x16 -> 64x64 per wave

    // Staging decomposition: each thread handles one 8-float chunk per round.
    // 128 rows * 8 chunks = 1024 chunk-slots; 256 threads -> 4 rounds/matrix.
    const int srow   = t >> 3;  // 0..31
    const int schunk = t & 7;   // 0..7 (8 bf16 = one 16B LDS unit)

    for (int kt = 0; kt < Dk / BK; ++kt) {
        const int kg = kt * BK + schunk * 8;
        // ---- stage A (h) ----
        #pragma unroll
        for (int r = 0; r < 4; ++r) {
            const int row = srow + r * 32;
            const float* src = hx + (size_t)(rowBase + row) * Dk + kg;
            float4 f0 = *(const float4*)(src);
            float4 f1 = *(const float4*)(src + 4);
            unsigned p0 = pack_bf16x2(f0.x, f0.y);
            unsigned p1 = pack_bf16x2(f0.z, f0.w);
            unsigned p2 = pack_bf16x2(f1.x, f1.y);
            unsigned p3 = pack_bf16x2(f1.z, f1.w);
            const int off = row * BK + ((schunk ^ (row & 7)) << 3); // XOR-swizzled 16B unit
            *(uint4*)(&As[off]) = make_uint4(p0, p1, p2, p3);
        }
        // ---- stage B (W) ----
        #pragma unroll
        for (int r = 0; r < 4; ++r) {
            const int row = srow + r * 32;
            const float* src = wx + (size_t)(colBase + row) * Dk + kg;
            float4 f0 = *(const float4*)(src);
            float4 f1 = *(const float4*)(src + 4);
            unsigned p0 = pack_bf16x2(f0.x, f0.y);
            unsigned p1 = pack_bf16x2(f0.z, f0.w);
            unsigned p2 = pack_bf16x2(f1.x, f1.y);
            unsigned p3 = pack_bf16x2(f1.z, f1.w);
            const int off = row * BK + ((schunk ^ (row & 7)) << 3);
            *(uint4*)(&Bs[off]) = make_uint4(p0, p1, p2, p3);
        }
        __syncthreads();

        // ---- compute: 2 K-subtiles of 32, 16 MFMA each ----
        #pragma unroll
        for (int ks = 0; ks < 2; ++ks) {
            bf16x8 av[4], bv[4];
            const int unit = ks * 4 + l4;
            #pragma unroll
            for (int m = 0; m < 4; ++m) {
                const int row = wrow * 64 + m * 16 + l15;
                const int off = row * BK + ((unit ^ (row & 7)) << 3);
                av[m] = __builtin_bit_cast(bf16x8, *(const short8*)(&As[off]));
            }
            #pragma unroll
            for (int n = 0; n < 4; ++n) {
                const int row = wcol * 64 + n * 16 + l15;
                const int off = row * BK + ((unit ^ (row & 7)) << 3);
                bv[n] = __builtin_bit_cast(bf16x8, *(const short8*)(&Bs[off]));
            }
            #pragma unroll
            for (int m = 0; m < 4; ++m)
                #pragma unroll
                for (int n = 0; n < 4; ++n)
                    acc[m][n] = __builtin_amdgcn_mfma_f32_16x16x32_bf16(
                        av[m], bv[n], acc[m][n], 0, 0, 0);
        }
        __syncthreads();
    }

    // ---- epilogue: per-row max and sum_exp over this block's 128 columns ----
    // C/D layout (m89): col = lane&15, row = (lane>>4)*4 + reg.
    float wmax[4][4];
    #pragma unroll
    for (int m = 0; m < 4; ++m) {
        #pragma unroll
        for (int r = 0; r < 4; ++r) {
            float v = fmaxf(fmaxf(acc[m][0][r], acc[m][1][r]),
                            fmaxf(acc[m][2][r], acc[m][3][r]));
            v = fmaxf(v, __shfl_xor(v, 1));
            v = fmaxf(v, __shfl_xor(v, 2));
            v = fmaxf(v, __shfl_xor(v, 4));
            v = fmaxf(v, __shfl_xor(v, 8));
            wmax[m][r] = v;  // max over this wave's 64 columns for one row
        }
    }
    if (l15 == 0) {
        #pragma unroll
        for (int m = 0; m < 4; ++m)
            #pragma unroll
            for (int r = 0; r < 4; ++r)
                redmax[wrow * 64 + m * 16 + l4 * 4 + r][wcol] = wmax[m][r];
    }
    __syncthreads();

    #pragma unroll
    for (int m = 0; m < 4; ++m) {
        #pragma unroll
        for (int r = 0; r < 4; ++r) {
            const int row = wrow * 64 + m * 16 + l4 * 4 + r;
            const float M = fmaxf(redmax[row][0], redmax[row][1]);
            float s = __expf(acc[m][0][r] - M) + __expf(acc[m][1][r] - M)
                    + __expf(acc[m][2][r] - M) + __expf(acc[m][3][r] - M);
            s += __shfl_xor(s, 1);
            s += __shfl_xor(s, 2);
            s += __shfl_xor(s, 4);
            s += __shfl_xor(s, 8);
            if (l15 == 0) redsum[row][wcol] = s;
        }
    }
    __syncthreads();

    if (wcol == 0 && l15 == 0) {
        #pragma unroll
        for (int m = 0; m < 4; ++m)
            #pragma unroll
            for (int r = 0; r < 4; ++r) {
                const int row = wrow * 64 + m * 16 + l4 * 4 + r;
                const float M = fmaxf(redmax[row][0], redmax[row][1]);
                const float S = redsum[row][0] + redsum[row][1];
                const size_t o = (size_t)(rowBase + row) * NTP + blockIdx.y;
                pmax[o] = M;
                psum[o] = S;
            }
    }
}

// Kernel 2: one wave per row — combine 250 tile partials into logsumexp,
// compute the target logit in exact fp32, emit per-row nll.
__global__ __launch_bounds__(256)
void lce_combine(const float* __restrict__ hx, const float* __restrict__ wx,
                 const int* __restrict__ tgt,
                 const float* __restrict__ pmax, const float* __restrict__ psum,
                 float* __restrict__ nll) {
    const int row  = (blockIdx.x * blockDim.x + threadIdx.x) >> 6;
    const int lane = threadIdx.x & 63;
    if (row >= Nrows) return;

    float pm[4], ps[4];
    float m = -INFINITY;
    #pragma unroll
    for (int i = 0; i < 4; ++i) {
        const int ti = lane + i * 64;
        const bool ok = ti < NT;
        pm[i] = ok ? pmax[(size_t)row * NTP + ti] : -INFINITY;
        ps[i] = ok ? psum[(size_t)row * NTP + ti] : 0.0f;
        m = fmaxf(m, pm[i]);
    }
    #pragma unroll
    for (int d = 1; d < 64; d <<= 1) m = fmaxf(m, __shfl_xor(m, d));
    float s = 0.0f;
    #pragma unroll
    for (int i = 0; i < 4; ++i) s += ps[i] * __expf(pm[i] - m);
    #pragma unroll
    for (int d = 1; d < 64; d <<= 1) s += __shfl_xor(s, d);
    const float lse = m + __logf(s);

    const int tg = tgt[row];
    const bool valid = (tg != IGNORE_INDEX);
    const int tw = valid ? tg : 0;
    const float* hr = hx + (size_t)row * Dk;
    const float* wr = wx + (size_t)tw * Dk;
    float acc = 0.0f;
    #pragma unroll
    for (int i = 0; i < 8; ++i) {
        const int off = lane * 4 + i * 256;
        float4 a = *(const float4*)(hr + off);
        float4 b = *(const float4*)(wr + off);
        acc += a.x * b.x + a.y * b.y + a.z * b.z + a.w * b.w;
    }
    #pragma unroll
    for (int d = 1; d < 64; d <<= 1) acc += __shfl_xor(acc, d);

    if (lane == 0) nll[row] = valid ? (lse - acc) : 0.0f;
}

// Kernel 3: deterministic single-block reduction -> scalar loss.
__global__ __launch_bounds__(1024)
void lce_finalize(const float* __restrict__ nll, const int* __restrict__ tgt,
                  float* __restrict__ out) {
    __shared__ float ssum[1024];
    __shared__ float scnt[1024];
    const int t = threadIdx.x;
    float s = 0.0f, c = 0.0f;
    for (int i = t; i < Nrows; i += 1024) {
        s += nll[i];
        c += (tgt[i] != IGNORE_INDEX) ? 1.0f : 0.0f;
    }
    ssum[t] = s;
    scnt[t] = c;
    __syncthreads();
    for (int d = 512; d > 0; d >>= 1) {
        if (t < d) { ssum[t] += ssum[t + d]; scnt[t] += scnt[t + d]; }
        __syncthreads();
    }
    if (t == 0) out[0] = (scnt[0] > 0.0f) ? ssum[0] / scnt[0] : ssum[0];
}

extern "C" void kernel_launch(void* const* d_in, const int* in_sizes, int n_in,
                              void* d_out, int out_size, void* d_ws, size_t ws_size,
                              hipStream_t stream) {
    const float* hx  = (const float*)d_in[0];  // [8192, 2048] f32
    const float* wx  = (const float*)d_in[1];  // [32000, 2048] f32
    const int*   tgt = (const int*)d_in[2];    // [8192] int
    float* out = (float*)d_out;

    // Workspace layout (floats): pmax[8192*256] | psum[8192*256] | nll[8192]
    float* pmax = (float*)d_ws;
    float* psum = pmax + (size_t)Nrows * NTP;
    float* nll  = psum + (size_t)Nrows * NTP;

    lce_gemm_lse<<<dim3(Nrows / BM, NT), 256, 0, stream>>>(hx, wx, pmax, psum);
    lce_combine<<<dim3((Nrows * 64) / 256), 256, 0, stream>>>(hx, wx, tgt, pmax, psum, nll);
    lce_finalize<<<1, 1024, 0, stream>>>(nll, tgt, out);
}

// Round 2
// 1152.170 us; speedup vs baseline: 2.3619x; 2.3619x over previous
//
#include <hip/hip_runtime.h>
#include <hip/hip_bf16.h>

#define IGNORE_INDEX (-100)

// Problem constants (fixed by the reference setup).
constexpr int Nrows = 8192;   // B*S
constexpr int Dk    = 2048;   // hidden
constexpr int Vv    = 32000;  // vocab

// GEMM tiling.
constexpr int BM = 128;
constexpr int BN = 128;
constexpr int BK = 64;
constexpr int NT  = Vv / BN;  // 250 vocab tiles
constexpr int NTP = 256;      // padded stride for partials

typedef __attribute__((ext_vector_type(8))) short   short8;
typedef __attribute__((ext_vector_type(8))) __bf16  bf16x8;
typedef __attribute__((ext_vector_type(4))) float   f32x4;

typedef const __attribute__((address_space(1))) void* gptr_t;
typedef __attribute__((address_space(3))) void*       lptr_t;

static __device__ __forceinline__ unsigned pack_bf16x2(float x, float y) {
    __hip_bfloat162 h = __float22bfloat162_rn(make_float2(x, y));
    unsigned u;
    __builtin_memcpy(&u, &h, 4);
    return u;
}

// ---------------------------------------------------------------------------
// Kernel 0: fp32 -> bf16 cast (vectorized, 8 elems/thread/iter, grid-stride).
// ---------------------------------------------------------------------------
__global__ __launch_bounds__(256)
void lce_cast_bf16(const float* __restrict__ src, unsigned short* __restrict__ dst,
                   int n8) {
    int i = blockIdx.x * blockDim.x + threadIdx.x;
    const int stride = gridDim.x * blockDim.x;
    for (; i < n8; i += stride) {
        const float4 f0 = ((const float4*)src)[(size_t)i * 2];
        const float4 f1 = ((const float4*)src)[(size_t)i * 2 + 1];
        uint4 o = make_uint4(pack_bf16x2(f0.x, f0.y), pack_bf16x2(f0.z, f0.w),
                             pack_bf16x2(f1.x, f1.y), pack_bf16x2(f1.z, f1.w));
        ((uint4*)dst)[i] = o;
    }
}

// ---------------------------------------------------------------------------
// Kernel 1 (fast path): bf16 GEMM-LSE, m97 structure.
// global_load_lds width=16, linear LDS dest, swizzle applied by permuting the
// GLOBAL source chunk (rule #21) and un-permuting on the ds_read side.
// ---------------------------------------------------------------------------
__global__ __launch_bounds__(256, 2)
void lce_gemm_lse_bf16(const unsigned short* __restrict__ ax,
                       const unsigned short* __restrict__ bx,
                       float* __restrict__ pmax, float* __restrict__ psum) {
    __shared__ unsigned short As[BM * BK];
    __shared__ unsigned short Bs[BN * BK];
    __shared__ float redmax[BM][2];
    __shared__ float redsum[BM][2];

    const int t    = threadIdx.x;
    const int lane = t & 63;
    const int wid  = t >> 6;
    const int wrow = wid >> 1;   // 0..1
    const int wcol = wid & 1;    // 0..1
    const int l15  = lane & 15;
    const int l4   = lane >> 4;

    const int rowBase = blockIdx.x * BM;
    const int colBase = blockIdx.y * BN;

    f32x4 acc[4][4] = {};

    for (int kt = 0; kt < Dk / BK; ++kt) {
        const int kg = kt * BK;
        // ---- stage A and B via global_load_lds (16B/lane) ----
        // chunk c = r*256 + t covers LDS slot c (16B units, linear);
        // slot (row = c>>3, su = c&7) must hold global unit gu = su ^ (row&7).
        #pragma unroll
        for (int r = 0; r < 4; ++r) {
            const int c   = r * 256 + t;
            const int row = c >> 3;
            const int gu  = (c & 7) ^ (row & 7);
            const unsigned short* gsrc =
                ax + (size_t)(rowBase + row) * Dk + kg + gu * 8;
            __builtin_amdgcn_global_load_lds(
                (gptr_t)gsrc, (lptr_t)&As[(r * 256 + wid * 64) * 8], 16, 0, 0);
        }
        #pragma unroll
        for (int r = 0; r < 4; ++r) {
            const int c   = r * 256 + t;
            const int row = c >> 3;
            const int gu  = (c & 7) ^ (row & 7);
            const unsigned short* gsrc =
                bx + (size_t)(colBase + row) * Dk + kg + gu * 8;
            __builtin_amdgcn_global_load_lds(
                (gptr_t)gsrc, (lptr_t)&Bs[(r * 256 + wid * 64) * 8], 16, 0, 0);
        }
        __syncthreads();

        // ---- compute: 2 K-subtiles of 32, 16 MFMA each ----
        #pragma unroll
        for (int ks = 0; ks < 2; ++ks) {
            bf16x8 av[4], bv[4];
            const int unit = ks * 4 + l4;
            #pragma unroll
            for (int m = 0; m < 4; ++m) {
                const int row = wrow * 64 + m * 16 + l15;
                const int off = row * BK + ((unit ^ (row & 7)) << 3);
                av[m] = __builtin_bit_cast(bf16x8, *(const short8*)(&As[off]));
            }
            #pragma unroll
            for (int n = 0; n < 4; ++n) {
                const int row = wcol * 64 + n * 16 + l15;
                const int off = row * BK + ((unit ^ (row & 7)) << 3);
                bv[n] = __builtin_bit_cast(bf16x8, *(const short8*)(&Bs[off]));
            }
            #pragma unroll
            for (int m = 0; m < 4; ++m)
                #pragma unroll
                for (int n = 0; n < 4; ++n)
                    acc[m][n] = __builtin_amdgcn_mfma_f32_16x16x32_bf16(
                        av[m], bv[n], acc[m][n], 0, 0, 0);
        }
        __syncthreads();
    }

    // ---- epilogue: per-row max and sum_exp over this block's 128 columns ----
    float wmax[4][4];
    #pragma unroll
    for (int m = 0; m < 4; ++m) {
        #pragma unroll
        for (int r = 0; r < 4; ++r) {
            float v = fmaxf(fmaxf(acc[m][0][r], acc[m][1][r]),
                            fmaxf(acc[m][2][r], acc[m][3][r]));
            v = fmaxf(v, __shfl_xor(v, 1));
            v = fmaxf(v, __shfl_xor(v, 2));
            v = fmaxf(v, __shfl_xor(v, 4));
            v = fmaxf(v, __shfl_xor(v, 8));
            wmax[m][r] = v;
        }
    }
    if (l15 == 0) {
        #pragma unroll
        for (int m = 0; m < 4; ++m)
            #pragma unroll
            for (int r = 0; r < 4; ++r)
                redmax[wrow * 64 + m * 16 + l4 * 4 + r][wcol] = wmax[m][r];
    }
    __syncthreads();

    #pragma unroll
    for (int m = 0; m < 4; ++m) {
        #pragma unroll
        for (int r = 0; r < 4; ++r) {
            const int row = wrow * 64 + m * 16 + l4 * 4 + r;
            const float M = fmaxf(redmax[row][0], redmax[row][1]);
            float s = __expf(acc[m][0][r] - M) + __expf(acc[m][1][r] - M)
                    + __expf(acc[m][2][r] - M) + __expf(acc[m][3][r] - M);
            s += __shfl_xor(s, 1);
            s += __shfl_xor(s, 2);
            s += __shfl_xor(s, 4);
            s += __shfl_xor(s, 8);
            if (l15 == 0) redsum[row][wcol] = s;
        }
    }
    __syncthreads();

    if (wcol == 0 && l15 == 0) {
        #pragma unroll
        for (int m = 0; m < 4; ++m)
            #pragma unroll
            for (int r = 0; r < 4; ++r) {
                const int row = wrow * 64 + m * 16 + l4 * 4 + r;
                const float M = fmaxf(redmax[row][0], redmax[row][1]);
                const float S = redsum[row][0] + redsum[row][1];
                const size_t o = (size_t)(rowBase + row) * NTP + blockIdx.y;
                pmax[o] = M;
                psum[o] = S;
            }
    }
}

// ---------------------------------------------------------------------------
// Kernel 1 (fallback, round-1 version): fp32 reg-staged GEMM-LSE. Used only
// if ws_size cannot hold the bf16 copies.
// ---------------------------------------------------------------------------
__global__ __launch_bounds__(256, 2)
void lce_gemm_lse(const float* __restrict__ hx, const float* __restrict__ wx,
                  float* __restrict__ pmax, float* __restrict__ psum) {
    __shared__ unsigned short As[BM * BK];
    __shared__ unsigned short Bs[BN * BK];
    __shared__ float redmax[BM][2];
    __shared__ float redsum[BM][2];

    const int t    = threadIdx.x;
    const int lane = t & 63;
    const int wid  = t >> 6;
    const int wrow = wid >> 1;
    const int wcol = wid & 1;
    const int l15  = lane & 15;
    const int l4   = lane >> 4;

    const int rowBase = blockIdx.x * BM;
    const int colBase = blockIdx.y * BN;

    f32x4 acc[4][4] = {};

    const int srow   = t >> 3;
    const int schunk = t & 7;

    for (int kt = 0; kt < Dk / BK; ++kt) {
        const int kg = kt * BK + schunk * 8;
        #pragma unroll
        for (int r = 0; r < 4; ++r) {
            const int row = srow + r * 32;
            const float* src = hx + (size_t)(rowBase + row) * Dk + kg;
            float4 f0 = *(const float4*)(src);
            float4 f1 = *(const float4*)(src + 4);
            const int off = row * BK + ((schunk ^ (row & 7)) << 3);
            *(uint4*)(&As[off]) = make_uint4(
                pack_bf16x2(f0.x, f0.y), pack_bf16x2(f0.z, f0.w),
                pack_bf16x2(f1.x, f1.y), pack_bf16x2(f1.z, f1.w));
        }
        #pragma unroll
        for (int r = 0; r < 4; ++r) {
            const int row = srow + r * 32;
            const float* src = wx + (size_t)(colBase + row) * Dk + kg;
            float4 f0 = *(const float4*)(src);
            float4 f1 = *(const float4*)(src + 4);
            const int off = row * BK + ((schunk ^ (row & 7)) << 3);
            *(uint4*)(&Bs[off]) = make_uint4(
                pack_bf16x2(f0.x, f0.y), pack_bf16x2(f0.z, f0.w),
                pack_bf16x2(f1.x, f1.y), pack_bf16x2(f1.z, f1.w));
        }
        __syncthreads();

        #pragma unroll
        for (int ks = 0; ks < 2; ++ks) {
            bf16x8 av[4], bv[4];
            const int unit = ks * 4 + l4;
            #pragma unroll
            for (int m = 0; m < 4; ++m) {
                const int row = wrow * 64 + m * 16 + l15;
                const int off = row * BK + ((unit ^ (row & 7)) << 3);
                av[m] = __builtin_bit_cast(bf16x8, *(const short8*)(&As[off]));
            }
            #pragma unroll
            for (int n = 0; n < 4; ++n) {
                const int row = wcol * 64 + n * 16 + l15;
                const int off = row * BK + ((unit ^ (row & 7)) << 3);
                bv[n] = __builtin_bit_cast(bf16x8, *(const short8*)(&Bs[off]));
            }
            #pragma unroll
            for (int m = 0; m < 4; ++m)
                #pragma unroll
                for (int n = 0; n < 4; ++n)
                    acc[m][n] = __builtin_amdgcn_mfma_f32_16x16x32_bf16(
                        av[m], bv[n], acc[m][n], 0, 0, 0);
        }
        __syncthreads();
    }

    float wmax[4][4];
    #pragma unroll
    for (int m = 0; m < 4; ++m) {
        #pragma unroll
        for (int r = 0; r < 4; ++r) {
            float v = fmaxf(fmaxf(acc[m][0][r], acc[m][1][r]),
                            fmaxf(acc[m][2][r], acc[m][3][r]));
            v = fmaxf(v, __shfl_xor(v, 1));
            v = fmaxf(v, __shfl_xor(v, 2));
            v = fmaxf(v, __shfl_xor(v, 4));
            v = fmaxf(v, __shfl_xor(v, 8));
            wmax[m][r] = v;
        }
    }
    if (l15 == 0) {
        #pragma unroll
        for (int m = 0; m < 4; ++m)
            #pragma unroll
            for (int r = 0; r < 4; ++r)
                redmax[wrow * 64 + m * 16 + l4 * 4 + r][wcol] = wmax[m][r];
    }
    __syncthreads();

    #pragma unroll
    for (int m = 0; m < 4; ++m) {
        #pragma unroll
        for (int r = 0; r < 4; ++r) {
            const int row = wrow * 64 + m * 16 + l4 * 4 + r;
            const float M = fmaxf(redmax[row][0], redmax[row][1]);
            float s = __expf(acc[m][0][r] - M) + __expf(acc[m][1][r] - M)
                    + __expf(acc[m][2][r] - M) + __expf(acc[m][3][r] - M);
            s += __shfl_xor(s, 1);
            s += __shfl_xor(s, 2);
            s += __shfl_xor(s, 4);
            s += __shfl_xor(s, 8);
            if (l15 == 0) redsum[row][wcol] = s;
        }
    }
    __syncthreads();

    if (wcol == 0 && l15 == 0) {
        #pragma unroll
        for (int m = 0; m < 4; ++m)
            #pragma unroll
            for (int r = 0; r < 4; ++r) {
                const int row = wrow * 64 + m * 16 + l4 * 4 + r;
                const float M = fmaxf(redmax[row][0], redmax[row][1]);
                const float S = redsum[row][0] + redsum[row][1];
                const size_t o = (size_t)(rowBase + row) * NTP + blockIdx.y;
                pmax[o] = M;
                psum[o] = S;
            }
    }
}

// ---------------------------------------------------------------------------
// Kernel 2: one wave per row — combine tile partials into logsumexp, exact
// fp32 target logit, per-row nll.
// ---------------------------------------------------------------------------
__global__ __launch_bounds__(256)
void lce_combine(const float* __restrict__ hx, const float* __restrict__ wx,
                 const int* __restrict__ tgt,
                 const float* __restrict__ pmax, const float* __restrict__ psum,
                 float* __restrict__ nll) {
    const int row  = (blockIdx.x * blockDim.x + threadIdx.x) >> 6;
    const int lane = threadIdx.x & 63;
    if (row >= Nrows) return;

    float pm[4], ps[4];
    float m = -INFINITY;
    #pragma unroll
    for (int i = 0; i < 4; ++i) {
        const int ti = lane + i * 64;
        const bool ok = ti < NT;
        pm[i] = ok ? pmax[(size_t)row * NTP + ti] : -INFINITY;
        ps[i] = ok ? psum[(size_t)row * NTP + ti] : 0.0f;
        m = fmaxf(m, pm[i]);
    }
    #pragma unroll
    for (int d = 1; d < 64; d <<= 1) m = fmaxf(m, __shfl_xor(m, d));
    float s = 0.0f;
    #pragma unroll
    for (int i = 0; i < 4; ++i) s += ps[i] * __expf(pm[i] - m);
    #pragma unroll
    for (int d = 1; d < 64; d <<= 1) s += __shfl_xor(s, d);
    const float lse = m + __logf(s);

    const int tg = tgt[row];
    const bool valid = (tg != IGNORE_INDEX);
    const int tw = valid ? tg : 0;
    const float* hr = hx + (size_t)row * Dk;
    const float* wr = wx + (size_t)tw * Dk;
    float acc = 0.0f;
    #pragma unroll
    for (int i = 0; i < 8; ++i) {
        const int off = lane * 4 + i * 256;
        float4 a = *(const float4*)(hr + off);
        float4 b = *(const float4*)(wr + off);
        acc += a.x * b.x + a.y * b.y + a.z * b.z + a.w * b.w;
    }
    #pragma unroll
    for (int d = 1; d < 64; d <<= 1) acc += __shfl_xor(acc, d);

    if (lane == 0) nll[row] = valid ? (lse - acc) : 0.0f;
}

// ---------------------------------------------------------------------------
// Kernel 3: deterministic single-block reduction -> scalar loss.
// ---------------------------------------------------------------------------
__global__ __launch_bounds__(1024)
void lce_finalize(const float* __restrict__ nll, const int* __restrict__ tgt,
                  float* __restrict__ out) {
    __shared__ float ssum[1024];
    __shared__ float scnt[1024];
    const int t = threadIdx.x;
    float s = 0.0f, c = 0.0f;
    for (int i = t; i < Nrows; i += 1024) {
        s += nll[i];
        c += (tgt[i] != IGNORE_INDEX) ? 1.0f : 0.0f;
    }
    ssum[t] = s;
    scnt[t] = c;
    __syncthreads();
    for (int d = 512; d > 0; d >>= 1) {
        if (t < d) { ssum[t] += ssum[t + d]; scnt[t] += scnt[t + d]; }
        __syncthreads();
    }
    if (t == 0) out[0] = (scnt[0] > 0.0f) ? ssum[0] / scnt[0] : ssum[0];
}

extern "C" void kernel_launch(void* const* d_in, const int* in_sizes, int n_in,
                              void* d_out, int out_size, void* d_ws, size_t ws_size,
                              hipStream_t stream) {
    const float* hx  = (const float*)d_in[0];  // [8192, 2048] f32
    const float* wx  = (const float*)d_in[1];  // [32000, 2048] f32
    const int*   tgt = (const int*)d_in[2];    // [8192] int
    float* out = (float*)d_out;

    // Workspace layout (bytes):
    //   pmax [Nrows*NTP f32] | psum [Nrows*NTP f32] | nll [Nrows f32]
    //   | hbf [Nrows*Dk bf16] | wbf [Vv*Dk bf16]
    float* pmax = (float*)d_ws;
    float* psum = pmax + (size_t)Nrows * NTP;
    float* nll  = psum + (size_t)Nrows * NTP;
    unsigned short* hbf = (unsigned short*)(nll + Nrows);
    unsigned short* wbf = hbf + (size_t)Nrows * Dk;

    const size_t need = (size_t)Nrows * NTP * 8 + (size_t)Nrows * 4
                      + ((size_t)Nrows * Dk + (size_t)Vv * Dk) * 2;

    if (ws_size >= need) {
        lce_cast_bf16<<<2048, 256, 0, stream>>>(hx, hbf, Nrows * Dk / 8);
        lce_cast_bf16<<<2048, 256, 0, stream>>>(wx, wbf, Vv * Dk / 8);
        lce_gemm_lse_bf16<<<dim3(Nrows / BM, NT), 256, 0, stream>>>(hbf, wbf, pmax, psum);
    } else {
        lce_gemm_lse<<<dim3(Nrows / BM, NT), 256, 0, stream>>>(hx, wx, pmax, psum);
    }
    lce_combine<<<dim3((Nrows * 64) / 256), 256, 0, stream>>>(hx, wx, tgt, pmax, psum, nll);
    lce_finalize<<<1, 1024, 0, stream>>>(nll, tgt, out);
}